// Round 2
// baseline (359.572 us; speedup 1.0000x reference)
//
#include <hip/hip_runtime.h>

// GraphConvolution: out[b,i,o] = relu( sum_f AX[b,i,f] * W[o,f] + bias[o] )
// AX[b,i,:] = w_i * (x[b,i-1,:] + x[b,i,:] + x[b,i+1,:]),  w_i = 1/2 ends, 1/3 interior
//
// R4: LDS-free, sync-free, latency-tolerant. R3 was latency-bound (2.5 TB/s, all
// pipes idle): VGPR=44 forced a ~3-load sliding window in staging, and reads were
// only in flight ~30% of block lifetime. Now each lane builds its MFMA A-fragment
// directly from global: 12 independent 16B loads per m-iter (3 clamped neighbor
// rows x 4 slices), weighted in fp32 regs (per-node weights handle boundaries --
// no zero-selects), converted to bf16 in-register. W/bias fragments also straight
// from global (L2-broadcast, once per wave). No LDS, no __syncthreads; loads issue
// continuously across the whole kernel.

#define NODES 55
#define F 48
#define BT 4              // batches per block (grid = BATCH/BT)

typedef __attribute__((ext_vector_type(8))) short short8_t;
typedef __attribute__((ext_vector_type(4))) float floatx4;

__device__ __forceinline__ unsigned short f2bf(float f) {
    union { float f; unsigned int u; } v; v.f = f;
    unsigned int u = v.u;
    u += 0x7FFFu + ((u >> 16) & 1u);   // round-to-nearest-even
    return (unsigned short)(u >> 16);
}

__device__ __forceinline__ short8_t pack8(floatx4 lo, floatx4 hi) {
    short8_t r;
    r[0] = (short)f2bf(lo[0]); r[1] = (short)f2bf(lo[1]);
    r[2] = (short)f2bf(lo[2]); r[3] = (short)f2bf(lo[3]);
    r[4] = (short)f2bf(hi[0]); r[5] = (short)f2bf(hi[1]);
    r[6] = (short)f2bf(hi[2]); r[7] = (short)f2bf(hi[3]);
    return r;
}

__global__ __launch_bounds__(256, 3)
void gconv_kernel(const float* __restrict__ x, const float* __restrict__ W,
                  const float* __restrict__ bias, float* __restrict__ out) {
    const int tid  = threadIdx.x;
    const int lane = tid & 63;
    const int wave = tid >> 6;
    const int col  = lane & 15;    // nb-index within a 16x16 tile (B-operand col)
    const int quad = lane >> 4;    // k = quad*8 + j (k-step 0)
    const int b0   = blockIdx.x * BT;

    const int ko1 = 32 + (quad & 1) * 8;   // k-step-1 feat base (quads 0,1 valid)
    const short8_t zero8 = {0, 0, 0, 0, 0, 0, 0, 0};

    // ---- W fragments straight from global (fp32 -> bf16), A-operand of MFMA ----
    // A[row=o][k=f]: lane reads W[nt*16+col][quad*8 .. +7] (and k-step 1 slice).
    short8_t wf[3][2];
#pragma unroll
    for (int nt = 0; nt < 3; ++nt) {
        const float* wr = W + (nt * 16 + col) * F;
        floatx4 w0 = *(const floatx4*)(wr + quad * 8);
        floatx4 w1 = *(const floatx4*)(wr + quad * 8 + 4);
        floatx4 w2 = *(const floatx4*)(wr + ko1);
        floatx4 w3 = *(const floatx4*)(wr + ko1 + 4);
        wf[nt][0] = pack8(w0, w1);
        short8_t t = pack8(w2, w3);
        // zero k=48..63 padding on the W side only; A side may hold finite garbage
        wf[nt][1] = (quad < 2) ? t : zero8;
    }

    // bias as float4 per o-tile: o = nt*16 + quad*4 + j
    floatx4 bv[3];
#pragma unroll
    for (int nt = 0; nt < 3; ++nt)
        bv[nt] = *(const floatx4*)&bias[nt * 16 + quad * 4];

#pragma unroll 2
    for (int it = 0; it < 4; ++it) {
        const int m    = wave + it * 4;     // 0..15; m=14,15 are fully store-masked
        const int nb   = m * 16 + col;      // row = node*4 + b_local
        const int node = nb >> 2;
        const int b_l  = nb & 3;

        // clamped neighbor rows
        int nm = node - 1; nm = nm < 0 ? 0 : (nm > 54 ? 54 : nm);
        int nc = node;     nc = nc > 54 ? 54 : nc;
        int np = node + 1; np = np > 54 ? 54 : np;

        // per-node weights: interior 1/3 each; node0 -> (0,.5,.5); node54 -> (.5,.5,0)
        const float ONE3 = 0.33333333333333333f;
        const float wl = (node == 0) ? 0.0f : ((node >= 54) ? 0.5f : ONE3);
        const float wm = (node == 0 || node >= 54) ? 0.5f : ONE3;
        const float wr_ = (node == 0) ? 0.5f : ((node >= 54) ? 0.0f : ONE3);

        const float* r0 = x + ((b0 + b_l) * NODES + nm) * F;
        const float* r1 = x + ((b0 + b_l) * NODES + nc) * F;
        const float* r2 = x + ((b0 + b_l) * NODES + np) * F;

        // ---- 12 independent 16B loads, all issued before any use ----
        floatx4 X00 = *(const floatx4*)(r0 + quad * 8);
        floatx4 X01 = *(const floatx4*)(r0 + quad * 8 + 4);
        floatx4 X02 = *(const floatx4*)(r0 + ko1);
        floatx4 X03 = *(const floatx4*)(r0 + ko1 + 4);
        floatx4 X10 = *(const floatx4*)(r1 + quad * 8);
        floatx4 X11 = *(const floatx4*)(r1 + quad * 8 + 4);
        floatx4 X12 = *(const floatx4*)(r1 + ko1);
        floatx4 X13 = *(const floatx4*)(r1 + ko1 + 4);
        floatx4 X20 = *(const floatx4*)(r2 + quad * 8);
        floatx4 X21 = *(const floatx4*)(r2 + quad * 8 + 4);
        floatx4 X22 = *(const floatx4*)(r2 + ko1);
        floatx4 X23 = *(const floatx4*)(r2 + ko1 + 4);

        // ---- AX fragment in fp32 regs, then bf16 ----
        floatx4 A0a = wl * X00 + wm * X10 + wr_ * X20;
        floatx4 A0b = wl * X01 + wm * X11 + wr_ * X21;
        floatx4 A1a = wl * X02 + wm * X12 + wr_ * X22;
        floatx4 A1b = wl * X03 + wm * X13 + wr_ * X23;
        short8_t a0 = pack8(A0a, A0b);
        short8_t a1 = pack8(A1a, A1b);   // quads 2,3: finite junk x zero W = 0

        floatx4 acc0 = {0.f, 0.f, 0.f, 0.f};
        floatx4 acc1 = {0.f, 0.f, 0.f, 0.f};
        floatx4 acc2 = {0.f, 0.f, 0.f, 0.f};
        acc0 = __builtin_amdgcn_mfma_f32_16x16x32_bf16(wf[0][0], a0, acc0, 0, 0, 0);
        acc1 = __builtin_amdgcn_mfma_f32_16x16x32_bf16(wf[1][0], a0, acc1, 0, 0, 0);
        acc2 = __builtin_amdgcn_mfma_f32_16x16x32_bf16(wf[2][0], a0, acc2, 0, 0, 0);
        acc0 = __builtin_amdgcn_mfma_f32_16x16x32_bf16(wf[0][1], a1, acc0, 0, 0, 0);
        acc1 = __builtin_amdgcn_mfma_f32_16x16x32_bf16(wf[1][1], a1, acc1, 0, 0, 0);
        acc2 = __builtin_amdgcn_mfma_f32_16x16x32_bf16(wf[2][1], a1, acc2, 0, 0, 0);

        // epilogue: D layout col=lane&15 (-> nb), row=quad*4+j (-> o)  [m89-verified]
        if (node < NODES) {
            float* op = out + ((b0 + b_l) * NODES + node) * F + quad * 4;
            floatx4 v0 = acc0 + bv[0];
            floatx4 v1 = acc1 + bv[1];
            floatx4 v2 = acc2 + bv[2];
#pragma unroll
            for (int j = 0; j < 4; ++j) {
                v0[j] = v0[j] > 0.f ? v0[j] : 0.f;
                v1[j] = v1[j] > 0.f ? v1[j] : 0.f;
                v2[j] = v2[j] > 0.f ? v2[j] : 0.f;
            }
            *(floatx4*)(op)      = v0;   // o = quad*4 + j
            *(floatx4*)(op + 16) = v1;   // o = 16 + ...
            *(floatx4*)(op + 32) = v2;   // o = 32 + ...
        }
    }
}

extern "C" void kernel_launch(void* const* d_in, const int* in_sizes, int n_in,
                              void* d_out, int out_size, void* d_ws, size_t ws_size,
                              hipStream_t stream) {
    const float* x    = (const float*)d_in[0];
    const float* W    = (const float*)d_in[1];
    const float* bias = (const float*)d_in[2];
    float* out = (float*)d_out;
    const int BATCH = 16384;
    dim3 grid(BATCH / BT);
    dim3 block(256);
    gconv_kernel<<<grid, block, 0, stream>>>(x, W, bias, out);
}

// Round 3
// 319.977 us; speedup vs baseline: 1.1237x; 1.1237x over previous
//
#include <hip/hip_runtime.h>

// GraphConvolution: out[b,i,o] = relu( sum_f AX[b,i,f] * W[o,f] + bias[o] )
// AX[b,i,:] = w_i * (x[b,i-1,:] + x[b,i,:] + x[b,i+1,:]),  w_i = 1/2 ends, 1/3 interior
//
// R5: double-buffered persistent pipeline. R3 was latency-bound because reads were
// only in flight during the staging phase (~35% duty); R4 (LDS-free gather) proved
// per-iter load->use distance of zero is worse. Now each block owns 8 tiles and
// software-pipelines: issue tile t+1's 13 clamped float4 loads into registers ->
// compute tile t from LDS (MFMA + float4 stores) -> weighted-smooth + ds_write
// tile t+1 into the other buffer -> sync. Loads are issued right after a barrier
// and consumed before the next one, so barriers never drain the prefetch; HBM reads
// stay outstanding through compute. Boundary handling via per-node weights (halo
// gets weight 0) -- no zero-selects. launch_bounds(256,2): 256-VGPR budget keeps
// the 52 staged VGPRs live across compute. LDS 55.5 KB -> 2 blocks/CU.

#define NODES 55
#define F 48
#define BT 4               // batches per tile
#define ROWS 224           // 56 padded nodes * BT; rows 220..223 zeroed
#define ST 56              // LDS row stride in bf16 elems (112 B)
#define TPB 8              // tiles per block
#define NBLOCKS 512        // 512 * 8 * 4 = 16384 batches

typedef __attribute__((ext_vector_type(8))) short short8_t;
typedef __attribute__((ext_vector_type(4))) float floatx4;

__device__ __forceinline__ unsigned short f2bf(float f) {
    union { float f; unsigned int u; } v; v.f = f;
    unsigned int u = v.u;
    u += 0x7FFFu + ((u >> 16) & 1u);   // round-to-nearest-even
    return (unsigned short)(u >> 16);
}

__global__ __launch_bounds__(256, 2)
void gconv_kernel(const float* __restrict__ x, const float* __restrict__ W,
                  const float* __restrict__ bias, float* __restrict__ out) {
    __shared__ unsigned short s_ax[2][ROWS * ST];  // 2 x 25088 B
    __shared__ unsigned short s_w[F * ST];         // 5376 B

    const int tid = threadIdx.x;

    // ---- zero pad rows 220..223 in BOTH buffers (once) ----
    if (tid >= 224) {   // 32 threads, 2 bufs * 4 rows * 12 uint2-chunks = 96 tasks
        for (int t = tid - 224; t < 96; t += 32) {
            int bu = t / 48, r = t - bu * 48;
            int row = 220 + r / 12, c = r - (r / 12) * 12;
            *(uint2*)&s_ax[bu][row * ST + c * 4] = make_uint2(0u, 0u);
        }
    }

    // ---- stage W (48x48 fp32 -> bf16), all threads ----
    for (int i = tid; i < F * F; i += 256) {
        int o = i / 48, f = i - o * 48;
        s_w[o * ST + f] = f2bf(W[i]);
    }

    // ---- staging decomposition: thread = (strip s 0..4, b_l 0..3, fq 0..11) ----
    const bool is_stager = tid < 240;
    const int s   = tid / 48;
    const int rem = tid - s * 48;
    const int sb  = rem / 12;            // b_local for staging
    const int fq  = rem - sb * 12;
    const int n0  = s * 11;
    const float4* xg = reinterpret_cast<const float4*>(x);

    float4 v[13];                        // staged rows n0-1 .. n0+11 (clamped)

    const int tile0 = blockIdx.x * TPB;

    auto stage_load = [&](int tile) {
        if (!is_stager) return;
        const int base = (tile * BT + sb) * (NODES * 12) + fq;
#pragma unroll
        for (int t = 0; t < 13; ++t) {
            int n = n0 - 1 + t;
            int nc = n < 0 ? 0 : (n > 54 ? 54 : n);
            v[t] = xg[base + nc * 12];   // raw clamped; halo neutralized by weights
        }
    };

    auto smooth_write = [&](int bu) {
        if (!is_stager) return;
        const float ONE3 = 0.33333333333333333f;
#pragma unroll
        for (int t = 0; t < 11; ++t) {
            int n = n0 + t;
            // neighbors: v[t]=row n-1 (clamped), v[t+1]=row n, v[t+2]=row n+1 (clamped)
            float wl = (n == 0) ? 0.0f : ((n == 54) ? 0.5f : ONE3);
            float wm = (n == 0 || n == 54) ? 0.5f : ONE3;
            float wr = (n == 54) ? 0.0f : ((n == 0) ? 0.5f : ONE3);
            float sx = v[t].x * wl + v[t + 1].x * wm + v[t + 2].x * wr;
            float sy = v[t].y * wl + v[t + 1].y * wm + v[t + 2].y * wr;
            float sz = v[t].z * wl + v[t + 1].z * wm + v[t + 2].z * wr;
            float sw = v[t].w * wl + v[t + 1].w * wm + v[t + 2].w * wr;
            unsigned int lo = (unsigned int)f2bf(sx) | ((unsigned int)f2bf(sy) << 16);
            unsigned int hi = (unsigned int)f2bf(sz) | ((unsigned int)f2bf(sw) << 16);
            *(uint2*)&s_ax[bu][(n * BT + sb) * ST + fq * 4] = make_uint2(lo, hi);
        }
    };

    // ---- first tile staged before the pipeline starts ----
    stage_load(tile0);
    smooth_write(0);
    __syncthreads();

    // ---- MFMA-phase constants (s_w ready after the sync) ----
    const int lane = tid & 63;
    const int wave = tid >> 6;
    const int col  = lane & 15;
    const int quad = lane >> 4;
    const short8_t zero8 = {0, 0, 0, 0, 0, 0, 0, 0};

    short8_t wf[3][2];
#pragma unroll
    for (int nt = 0; nt < 3; ++nt) {
        wf[nt][0] = *(const short8_t*)&s_w[(nt * 16 + col) * ST + quad * 8];
        short8_t t1 = *(const short8_t*)&s_w[(nt * 16 + col) * ST + 32 + (quad & 1) * 8];
        wf[nt][1] = (quad < 2) ? t1 : zero8;
    }
    floatx4 bv[3];
#pragma unroll
    for (int mt = 0; mt < 3; ++mt)
        bv[mt] = *(const floatx4*)&bias[mt * 16 + quad * 4];

    auto compute = [&](int bu, int tile) {
        const int b0 = tile * BT;
        for (int m = wave; m < 14; m += 4) {
            const int nb = m * 16 + col;          // row = node*4 + b_local
            short8_t a0 = *(const short8_t*)&s_ax[bu][nb * ST + quad * 8];
            short8_t t1 = *(const short8_t*)&s_ax[bu][nb * ST + 32 + (quad & 1) * 8];
            short8_t a1 = (quad < 2) ? t1 : zero8;

            floatx4 acc0 = {0.f, 0.f, 0.f, 0.f};
            floatx4 acc1 = {0.f, 0.f, 0.f, 0.f};
            floatx4 acc2 = {0.f, 0.f, 0.f, 0.f};
            acc0 = __builtin_amdgcn_mfma_f32_16x16x32_bf16(wf[0][0], a0, acc0, 0, 0, 0);
            acc1 = __builtin_amdgcn_mfma_f32_16x16x32_bf16(wf[1][0], a0, acc1, 0, 0, 0);
            acc2 = __builtin_amdgcn_mfma_f32_16x16x32_bf16(wf[2][0], a0, acc2, 0, 0, 0);
            acc0 = __builtin_amdgcn_mfma_f32_16x16x32_bf16(wf[0][1], a1, acc0, 0, 0, 0);
            acc1 = __builtin_amdgcn_mfma_f32_16x16x32_bf16(wf[1][1], a1, acc1, 0, 0, 0);
            acc2 = __builtin_amdgcn_mfma_f32_16x16x32_bf16(wf[2][1], a1, acc2, 0, 0, 0);

            // D layout: col=lane&15 (-> nb), row=quad*4+j (-> o)  [m89-verified]
            const int node = nb >> 2;
            const int b_l  = nb & 3;
            if (node < NODES) {
                float* op = out + ((b0 + b_l) * NODES + node) * F + quad * 4;
                floatx4 v0 = acc0 + bv[0];
                floatx4 v1 = acc1 + bv[1];
                floatx4 v2 = acc2 + bv[2];
#pragma unroll
                for (int j = 0; j < 4; ++j) {
                    v0[j] = v0[j] > 0.f ? v0[j] : 0.f;
                    v1[j] = v1[j] > 0.f ? v1[j] : 0.f;
                    v2[j] = v2[j] > 0.f ? v2[j] : 0.f;
                }
                *(floatx4*)(op)      = v0;
                *(floatx4*)(op + 16) = v1;
                *(floatx4*)(op + 32) = v2;
            }
        }
    };

    // ---- pipeline: issue t+1 loads | compute t | smooth-write t+1 | sync ----
    for (int t = 0; t < TPB; ++t) {
        if (t + 1 < TPB) stage_load(tile0 + t + 1);
        compute(t & 1, tile0 + t);
        if (t + 1 < TPB) {
            smooth_write((t + 1) & 1);
            __syncthreads();
        }
    }
}

extern "C" void kernel_launch(void* const* d_in, const int* in_sizes, int n_in,
                              void* d_out, int out_size, void* d_ws, size_t ws_size,
                              hipStream_t stream) {
    const float* x    = (const float*)d_in[0];
    const float* W    = (const float*)d_in[1];
    const float* bias = (const float*)d_in[2];
    float* out = (float*)d_out;
    dim3 grid(NBLOCKS);
    dim3 block(256);
    gconv_kernel<<<grid, block, 0, stream>>>(x, W, bias, out);
}